// Round 10
// baseline (167.186 us; speedup 1.0000x reference)
//
#include <hip/hip_runtime.h>
#include <hip/hip_cooperative_groups.h>

namespace cg = cooperative_groups;

// Problem constants (from reference setup_inputs)
constexpr int NPTS = 8192;   // points per batch
constexpr int NQ   = 2048;   // query points per batch
constexpr int NC   = 64;     // feature channels
constexpr int NS   = 32;     // nsample
constexpr int NCH  = 3 + 1 + NC;           // 68 output channels
constexpr int CS   = NQ * NS;              // channel stride in output (floats)

// Workspace layout (floats): ftr B*NPTS*NC | soa B*3*NPTS | idx B*NQ*NS (fallback)

// R10: ONE cooperative kernel (T: transpose+SoA -> grid.sync -> S: scan ->
// G: group). Rationale: R4->R7 (-1 node) = -9.5 us while three scan rewrites
// moved only +-2 us => per-node overhead dominates the unattributed time.
// Indices stay in LDS (no gidx round-trip). Fallback to R9 2-kernel path if
// hipLaunchCooperativeKernel fails (e.g. capture-unsupported) -> neutral.

__device__ __forceinline__ unsigned prefix_popc(unsigned long long m) {
    return __builtin_amdgcn_mbcnt_hi((unsigned)(m >> 32),
           __builtin_amdgcn_mbcnt_lo((unsigned)m, 0u));
}

union FusedLds {
    float tile[NC][65];                                  // phase T (16.6 KB)
    struct { int idx[16][NS]; float ldsc[NC][33]; } sg;  // phases S,G (10.3 KB)
};

__global__ __launch_bounds__(512, 4) void fused_kernel(
    const float* __restrict__ xyz,    // (B, NPTS, 3)
    const float* __restrict__ nxyz,   // (B, NQ, 3)
    const float* __restrict__ feat,   // (B, NC, NPTS)
    float* __restrict__ ftr,          // (B, NPTS, NC)
    float* __restrict__ soa,          // (B, 3, NPTS)
    float* __restrict__ out,          // (B, NCH, NQ, NS)
    int B)
{
    __shared__ FusedLds u;
    const int g = blockIdx.x;
    const int t = threadIdx.x;
    int b, r;                          // batch, tile/query-group within batch
    if (B == 4) { b = (g & 7) >> 1; r = ((g >> 3) << 1) | (g & 1); } // XCD-pair pin
    else        { b = g >> 7;       r = g & 127; }

    const float* xb = xyz + (size_t)b * NPTS * 3;
    float* xs = soa + (size_t)b * 3 * NPTS;
    float* ys = xs + NPTS;
    float* zs = ys + NPTS;

    // ---- phase T: one 64x64 feature-transpose tile + SoA for 64 points ----
    {
        const int n0 = r * 64;
        const float* fb = feat + (size_t)b * NC * NPTS;
        const int pl = t & 63;
        const int c0 = t >> 6;            // 0..7
        #pragma unroll
        for (int i = 0; i < 8; ++i) {     // coalesced 256B rows
            const int c = c0 + 8 * i;
            u.tile[c][pl] = fb[(size_t)c * NPTS + n0 + pl];
        }
        __syncthreads();
        float* tb = ftr + ((size_t)b * NPTS + n0) * NC;
        #pragma unroll
        for (int i = 0; i < 8; ++i) {     // coalesced 256B per point
            const int pp = c0 + 8 * i;
            tb[(size_t)pp * NC + pl] = u.tile[pl][pp];   // (pl*65+pp)%32: free
        }
        if (t < 64) {                     // SoA: 192 dwords/block, tiny
            const int i = n0 + t;
            xs[i] = xb[3 * i + 0];
            ys[i] = xb[3 * i + 1];
            zs[i] = xb[3 * i + 2];
        }
    }
    cg::this_grid().sync();               // ftr + soa visible grid-wide

    // ---- phase S: 16 queries/block, SoA global prefetch-2 ballot scan ----
    const int lane = t & 63;
    const int wave = t >> 6;              // 0..7, 2 sequential queries each
    for (int k = 0; k < 2; ++k) {
        const int qi = wave * 2 + k;
        const int p  = r * 16 + qi;
        int* idx_row = u.sg.idx[qi];

        const float qx = nxyz[((size_t)b * NQ + p) * 3 + 0];
        const float qy = nxyz[((size_t)b * NQ + p) * 3 + 1];
        const float qz = nxyz[((size_t)b * NQ + p) * 3 + 2];

        int cnt = 0;      // wave-uniform hit count
        int first = -1;   // wave-uniform first-hit index

        float x0 = xs[lane],      y0 = ys[lane],      z0 = zs[lane];
        float x1 = xs[64 + lane], y1 = ys[64 + lane], z1 = zs[64 + lane];

        for (int base = 0; base < NPTS; base += 64) {
            float xn = 0.f, yn = 0.f, zn = 0.f;
            const int pf = base + 128;
            if (pf < NPTS) {              // wave-uniform guard
                xn = xs[pf + lane]; yn = ys[pf + lane]; zn = zs[pf + lane];
            }
            // strict per-op rounding, reference evaluation order (q<1.0 is
            // discontinuous -> no FMA contraction allowed)
            const float dx = __fsub_rn(qx, x0);
            const float dy = __fsub_rn(qy, y0);
            const float dz = __fsub_rn(qz, z0);
            const float t0 = __fmul_rn(__fmul_rn(dx, dx), 25.0f);
            const float t1 = __fmul_rn(__fmul_rn(dy, dy), 6.25f);
            const float t2 = __fmul_rn(__fmul_rn(dz, dz), 25.0f);
            const float qv = __fadd_rn(__fadd_rn(t0, t1), t2);
            const bool hit = qv < 1.0f;

            const unsigned long long m = __ballot(hit);
            if (first < 0 && m != 0ull)
                first = base + __builtin_ctzll(m);       // wave-uniform
            if (hit) {
                const int pos = cnt + (int)prefix_popc(m);
                if (pos < NS) idx_row[pos] = base + lane;
            }
            cnt += __popcll(m);
            if (cnt >= NS) break;                        // uniform early exit
            x0 = x1; y0 = y1; z0 = z1;
            x1 = xn; y1 = yn; z1 = zn;
        }
        if (cnt < NS) {
            const int f = (cnt == 0) ? 0 : first;        // pad (0 if empty)
            if (lane < NS && lane >= cnt) idx_row[lane] = f;
        }

        // epilogue: lanes 0..31 emit channels 0..3 (xyz, 1/density)
        if (lane < NS) {
            const int s = lane;
            const int j = idx_row[s];                    // same-wave LDS RAW
            const float px = xs[j], py = ys[j], pz = zs[j];
            const float dx = __fsub_rn(px, qx);
            const float dy = __fsub_rn(py, qy);
            const float dz = __fsub_rn(pz, qz);
            const float d2 = __fadd_rn(__fadd_rn(__fmul_rn(dx, dx),
                                                 __fmul_rn(dy, dy)),
                                       __fmul_rn(dz, dz));
            const float dist = __fsqrt_rn(d2);
            const float arg  = __fdiv_rn(-__fmul_rn(dist, dist), 0.02f);
            const float density = __fmul_rn(expf(arg), 4.0f); // /0.25 == *4
            const float gd = __fdiv_rn(1.0f, density);        // inf underflow==ref

            float* ob = out + ((size_t)b * NCH * NQ + p) * NS + s;
            ob[0 * (size_t)CS] = px;
            ob[1 * (size_t)CS] = py;
            ob[2 * (size_t)CS] = pz;
            ob[3 * (size_t)CS] = gd;
        }
    }
    __syncthreads();                      // idx rows visible block-wide

    // ---- phase G: gather + LDS transpose + coalesced store, 16 queries ----
    const int cgi = t & 15;               // channel group (float4)
    const int sl  = t >> 4;               // sample 0..31
    const int cch = t >> 3;               // channel 0..63
    const int s4  = (t & 7) << 2;         // sample base
    for (int q = 0; q < 16; ++q) {
        const int p = r * 16 + q;
        const int j = u.sg.idx[q][sl];
        const float4 v = ((const float4*)(ftr + ((size_t)b * NPTS + j) * NC))[cgi];
        u.sg.ldsc[4 * cgi + 0][sl] = v.x; // bank (4cgi+i+sl)%32: ~2-way
        u.sg.ldsc[4 * cgi + 1][sl] = v.y;
        u.sg.ldsc[4 * cgi + 2][sl] = v.z;
        u.sg.ldsc[4 * cgi + 3][sl] = v.w;
        __syncthreads();
        float4 w;
        w.x = u.sg.ldsc[cch][s4 + 0];     // bank (cch+s4+i)%32: <=2-way
        w.y = u.sg.ldsc[cch][s4 + 1];
        w.z = u.sg.ldsc[cch][s4 + 2];
        w.w = u.sg.ldsc[cch][s4 + 3];
        float* op = out + (((size_t)b * NCH + 4 + cch) * NQ + p) * NS + s4;
        *(float4*)op = w;                 // 8 x 128B segments per wave store
        __syncthreads();                  // before next q overwrites ldsc
    }
}

// ===========================================================================
// Fallback path A (coop launch failed): R9 two-kernel pipeline.
// ===========================================================================
constexpr int LPTS = 5120;
constexpr int QPB2 = 16;
struct ScanLds { float pts[3][LPTS]; int idx[QPB2][NS]; };
union  KLds    { ScanLds s; float tile[2][NC][65]; };

__global__ __launch_bounds__(1024, 8) void scan_trans_kernel(
    const float* __restrict__ xyz, const float* __restrict__ nxyz,
    const float* __restrict__ feat, float* __restrict__ ftr,
    int* __restrict__ gidx, float* __restrict__ out, int ntrans)
{
    __shared__ KLds u;
    const int bx = blockIdx.x;
    const int t  = threadIdx.x;

    if (bx < ntrans) {
        const int b   = bx >> 6;
        const int tl2 = bx & 63;
        const int h   = t >> 9;
        const int v   = t & 511;
        const int pl  = v & 63;
        const int c0  = v >> 6;
        const int n0  = tl2 * 128 + h * 64;
        const float* fb = feat + (size_t)b * NC * NPTS;
        #pragma unroll
        for (int i = 0; i < 8; ++i) {
            const int c = c0 + 8 * i;
            u.tile[h][c][pl] = fb[(size_t)c * NPTS + n0 + pl];
        }
        __syncthreads();
        float* tb = ftr + ((size_t)b * NPTS + n0) * NC;
        #pragma unroll
        for (int i = 0; i < 8; ++i) {
            const int pp = c0 + 8 * i;
            tb[(size_t)pp * NC + pl] = u.tile[h][pl][pp];
        }
        return;
    }

    const int sb   = bx - ntrans;
    const int qpb  = NQ / QPB2;
    const int b    = sb / qpb;
    const int p0   = (sb - b * qpb) * QPB2;
    const int lane = t & 63;
    const int wave = t >> 6;
    const float* xb = xyz + (size_t)b * NPTS * 3;

    #pragma unroll
    for (int k = 0; k < 3 * LPTS / 1024; ++k) {
        const int g  = k * 1024 + t;
        const float val = xb[g];
        const int pt = g / 3;
        const int c  = g - 3 * pt;
        u.s.pts[c][pt] = val;
    }
    __syncthreads();

    const int p = p0 + wave;
    const float qx = nxyz[((size_t)b * NQ + p) * 3 + 0];
    const float qy = nxyz[((size_t)b * NQ + p) * 3 + 1];
    const float qz = nxyz[((size_t)b * NQ + p) * 3 + 2];

    int cnt = 0, first = -1;
    int* idx_row = u.s.idx[wave];

    for (int base = 0; base < LPTS; base += 128) {
        const int i0 = base + lane;
        const int i1 = i0 + 64;
        const float xA = u.s.pts[0][i0], xB = u.s.pts[0][i1];
        const float yA = u.s.pts[1][i0], yB = u.s.pts[1][i1];
        const float zA = u.s.pts[2][i0], zB = u.s.pts[2][i1];

        const float dxA = __fsub_rn(qx, xA);
        const float dyA = __fsub_rn(qy, yA);
        const float dzA = __fsub_rn(qz, zA);
        const float qA  = __fadd_rn(__fadd_rn(
                            __fmul_rn(__fmul_rn(dxA, dxA), 25.0f),
                            __fmul_rn(__fmul_rn(dyA, dyA), 6.25f)),
                            __fmul_rn(__fmul_rn(dzA, dzA), 25.0f));
        const float dxB = __fsub_rn(qx, xB);
        const float dyB = __fsub_rn(qy, yB);
        const float dzB = __fsub_rn(qz, zB);
        const float qB  = __fadd_rn(__fadd_rn(
                            __fmul_rn(__fmul_rn(dxB, dxB), 25.0f),
                            __fmul_rn(__fmul_rn(dyB, dyB), 6.25f)),
                            __fmul_rn(__fmul_rn(dzB, dzB), 25.0f));
        const bool hitA = qA < 1.0f;
        const bool hitB = qB < 1.0f;

        const unsigned long long m0 = __ballot(hitA);
        const unsigned long long m1 = __ballot(hitB);
        if (first < 0) {
            if (m0 != 0ull)      first = base + __builtin_ctzll(m0);
            else if (m1 != 0ull) first = base + 64 + __builtin_ctzll(m1);
        }
        if (hitA) {
            const int pos = cnt + (int)prefix_popc(m0);
            if (pos < NS) idx_row[pos] = i0;
        }
        const int c0 = __popcll(m0);
        if (hitB) {
            const int pos = cnt + c0 + (int)prefix_popc(m1);
            if (pos < NS) idx_row[pos] = i1;
        }
        cnt += c0 + __popcll(m1);
        if (cnt >= NS) break;
    }

    if (cnt < NS) {
        float x0 = xb[3 * (LPTS + lane) + 0];
        float y0 = xb[3 * (LPTS + lane) + 1];
        float z0 = xb[3 * (LPTS + lane) + 2];
        float x1 = xb[3 * (LPTS + 64 + lane) + 0];
        float y1 = xb[3 * (LPTS + 64 + lane) + 1];
        float z1 = xb[3 * (LPTS + 64 + lane) + 2];
        for (int base = LPTS; base < NPTS; base += 64) {
            float xn = 0.f, yn = 0.f, zn = 0.f;
            const int pf = base + 128;
            if (pf < NPTS) {
                xn = xb[3 * (pf + lane) + 0];
                yn = xb[3 * (pf + lane) + 1];
                zn = xb[3 * (pf + lane) + 2];
            }
            const float dx = __fsub_rn(qx, x0);
            const float dy = __fsub_rn(qy, y0);
            const float dz = __fsub_rn(qz, z0);
            const float t0 = __fmul_rn(__fmul_rn(dx, dx), 25.0f);
            const float t1 = __fmul_rn(__fmul_rn(dy, dy), 6.25f);
            const float t2 = __fmul_rn(__fmul_rn(dz, dz), 25.0f);
            const float qv = __fadd_rn(__fadd_rn(t0, t1), t2);
            const bool hit = qv < 1.0f;
            const unsigned long long m = __ballot(hit);
            if (first < 0 && m != 0ull) first = base + __builtin_ctzll(m);
            if (hit) {
                const int pos = cnt + (int)prefix_popc(m);
                if (pos < NS) idx_row[pos] = base + lane;
            }
            cnt += __popcll(m);
            if (cnt >= NS) break;
            x0 = x1; y0 = y1; z0 = z1;
            x1 = xn; y1 = yn; z1 = zn;
        }
    }

    if (cnt < NS) {
        const int f = (cnt == 0) ? 0 : first;
        if (lane < NS && lane >= cnt) idx_row[lane] = f;
    }

    if (lane < NS) {
        const int s = lane;
        const int j = idx_row[s];
        gidx[((size_t)b * NQ + p) * NS + s] = j;
        const float px = xb[3 * j + 0];
        const float py = xb[3 * j + 1];
        const float pz = xb[3 * j + 2];
        const float dx = __fsub_rn(px, qx);
        const float dy = __fsub_rn(py, qy);
        const float dz = __fsub_rn(pz, qz);
        const float d2 = __fadd_rn(__fadd_rn(__fmul_rn(dx, dx), __fmul_rn(dy, dy)),
                                   __fmul_rn(dz, dz));
        const float dist = __fsqrt_rn(d2);
        const float arg  = __fdiv_rn(-__fmul_rn(dist, dist), 0.02f);
        const float density = __fmul_rn(expf(arg), 4.0f);
        const float gd = __fdiv_rn(1.0f, density);

        float* ob = out + ((size_t)b * NCH * NQ + p) * NS + s;
        ob[0 * (size_t)CS] = px;
        ob[1 * (size_t)CS] = py;
        ob[2 * (size_t)CS] = pz;
        ob[3 * (size_t)CS] = gd;
    }
}

__global__ __launch_bounds__(512, 8) void group_kernel(
    const int* __restrict__ gidx, const float* __restrict__ ftr,
    float* __restrict__ out, int B)
{
    __shared__ float ldsc[NC][33];
    const int g = blockIdx.x;
    int b, p;
    if (B == 4) { b = (g & 7) >> 1; p = ((g >> 3) << 1) | (g & 1); }
    else        { b = g / NQ;       p = g - b * NQ; }
    const int tid = threadIdx.x;

    const int cg = tid & 15;
    const int sl = tid >> 4;
    const int j  = gidx[((size_t)b * NQ + p) * NS + sl];
    const float4 v = ((const float4*)(ftr + ((size_t)b * NPTS + j) * NC))[cg];
    ldsc[4 * cg + 0][sl] = v.x;
    ldsc[4 * cg + 1][sl] = v.y;
    ldsc[4 * cg + 2][sl] = v.z;
    ldsc[4 * cg + 3][sl] = v.w;
    __syncthreads();

    const int c  = tid >> 3;
    const int s4 = (tid & 7) << 2;
    float4 w;
    w.x = ldsc[c][s4 + 0];
    w.y = ldsc[c][s4 + 1];
    w.z = ldsc[c][s4 + 2];
    w.w = ldsc[c][s4 + 3];
    float* op = out + (((size_t)b * NCH + 4 + c) * NQ + p) * NS + s4;
    *(float4*)op = w;
}

// Fallback path B (tiny ws): R1-style fused direct kernel.
__global__ __launch_bounds__(512, 8) void ellip_direct_kernel(
    const float* __restrict__ xyz, const float* __restrict__ nxyz,
    const float* __restrict__ feat, float* __restrict__ out)
{
    __shared__ int idx_s[8][NS];
    const int b    = blockIdx.y;
    const int p0   = blockIdx.x * 8;
    const int tid  = threadIdx.x;
    const int lane = tid & 63;
    const int wave = tid >> 6;
    const float* xb = xyz + (size_t)b * NPTS * 3;
    {
        const int p = p0 + wave;
        const float qx = nxyz[((size_t)b * NQ + p) * 3 + 0];
        const float qy = nxyz[((size_t)b * NQ + p) * 3 + 1];
        const float qz = nxyz[((size_t)b * NQ + p) * 3 + 2];
        int cnt = 0, first = -1;
        for (int base = 0; base < NPTS; base += 64) {
            const int i = base + lane;
            const float dx = __fsub_rn(qx, xb[i * 3 + 0]);
            const float dy = __fsub_rn(qy, xb[i * 3 + 1]);
            const float dz = __fsub_rn(qz, xb[i * 3 + 2]);
            const float t0 = __fmul_rn(__fmul_rn(dx, dx), 25.0f);
            const float t1 = __fmul_rn(__fmul_rn(dy, dy), 6.25f);
            const float t2 = __fmul_rn(__fmul_rn(dz, dz), 25.0f);
            const float qv = __fadd_rn(__fadd_rn(t0, t1), t2);
            const bool hit = qv < 1.0f;
            const unsigned long long m = __ballot(hit);
            if (first < 0 && m != 0ull) first = base + __builtin_ctzll(m);
            if (hit) {
                const int pos = cnt + __popcll(m & ((1ull << lane) - 1ull));
                if (pos < NS) idx_s[wave][pos] = i;
            }
            cnt += __popcll(m);
            if (cnt >= NS) break;
        }
        if (cnt < NS) {
            const int f = (cnt == 0) ? 0 : first;
            if (lane < NS && lane >= cnt) idx_s[wave][lane] = f;
        }
    }
    __syncthreads();
    const int s = tid & 31;
    const int h = (tid >> 5) & 1;
    const int q = tid >> 6;
    const int p = p0 + q;
    const int j = idx_s[q][s];
    float* ob = out + ((size_t)b * NCH * NQ + p) * NS + s;
    if (h == 0) {
        const float qx = nxyz[((size_t)b * NQ + p) * 3 + 0];
        const float qy = nxyz[((size_t)b * NQ + p) * 3 + 1];
        const float qz = nxyz[((size_t)b * NQ + p) * 3 + 2];
        const float px = xb[j * 3 + 0], py = xb[j * 3 + 1], pz = xb[j * 3 + 2];
        const float dx = __fsub_rn(px, qx);
        const float dy = __fsub_rn(py, qy);
        const float dz = __fsub_rn(pz, qz);
        const float d2 = __fadd_rn(__fadd_rn(__fmul_rn(dx, dx), __fmul_rn(dy, dy)),
                                   __fmul_rn(dz, dz));
        const float dist = __fsqrt_rn(d2);
        const float arg  = __fdiv_rn(-__fmul_rn(dist, dist), 0.02f);
        const float gd = __fdiv_rn(1.0f, __fmul_rn(expf(arg), 4.0f));
        ob[0 * (size_t)CS] = px;
        ob[1 * (size_t)CS] = py;
        ob[2 * (size_t)CS] = pz;
        ob[3 * (size_t)CS] = gd;
    }
    const float* fb = feat + (size_t)b * NC * NPTS + j;
    #pragma unroll 4
    for (int c = h; c < NC; c += 2)
        ob[(size_t)(4 + c) * CS] = fb[(size_t)c * NPTS];
}

extern "C" void kernel_launch(void* const* d_in, const int* in_sizes, int n_in,
                              void* d_out, int out_size, void* d_ws, size_t ws_size,
                              hipStream_t stream) {
    const float* xyz  = (const float*)d_in[0];   // (B, 8192, 3)
    const float* nxyz = (const float*)d_in[1];   // (B, 2048, 3)
    const float* feat = (const float*)d_in[2];   // (B, 64, 8192)
    float* out = (float*)d_out;                  // (B, 68, 2048, 32)

    const int B = in_sizes[0] / (NPTS * 3);
    const size_t ftr_f = (size_t)B * NPTS * NC;
    const size_t soa_f = (size_t)B * 3 * NPTS;
    const size_t idx_f = (size_t)B * NQ * NS;
    const size_t need  = (ftr_f + soa_f + idx_f) * 4;

    if (ws_size >= need) {
        float* ftr = (float*)d_ws;
        float* soa = ftr + ftr_f;
        int*   idx = (int*)(soa + soa_f);

        // --- preferred: single cooperative kernel (512 blocks x 512 thr,
        //     2 blocks/CU co-resident on 256 CUs) ---
        const float* a0 = xyz; const float* a1 = nxyz; const float* a2 = feat;
        float* a3 = ftr; float* a4 = soa; float* a5 = out; int a6 = B;
        void* args[] = { &a0, &a1, &a2, &a3, &a4, &a5, &a6 };
        hipError_t e = hipLaunchCooperativeKernel(
            (const void*)fused_kernel, dim3(B * 128), dim3(512), args, 0, stream);
        if (e == hipSuccess) return;
        (void)hipGetLastError();                 // clear, fall back to R9 path

        const int ntrans = B * 64;
        const int nscan  = B * (NQ / QPB2);
        scan_trans_kernel<<<dim3(ntrans + nscan), 1024, 0, stream>>>(
            xyz, nxyz, feat, ftr, idx, out, ntrans);
        group_kernel<<<dim3(B * NQ), 512, 0, stream>>>(idx, ftr, out, B);
    } else {
        ellip_direct_kernel<<<dim3(NQ / 8, B), 512, 0, stream>>>(xyz, nxyz, feat, out);
    }
}

// Round 11
// 100.198 us; speedup vs baseline: 1.6686x; 1.6686x over previous
//
#include <hip/hip_runtime.h>

// Problem constants (from reference setup_inputs)
constexpr int NPTS = 8192;   // points per batch
constexpr int NQ   = 2048;   // query points per batch
constexpr int NC   = 64;     // feature channels
constexpr int NS   = 32;     // nsample
constexpr int NCH  = 3 + 1 + NC;           // 68 output channels
constexpr int CS   = NQ * NS;              // channel stride in output (floats)
constexpr int TP   = 2048;   // points per LDS scan tile
constexpr int QPB  = 8;      // queries per scan block (8 waves, 512 thr)

// Workspace layout (floats):  ftr : B*NPTS*NC  |  idx : B*NQ*NS (int32)

// R11 = R9 two-node structure (measured best), node-1 rebuilt at 512 thr:
//  - scan blocks: 8 queries/block, 2048-pt LDS tiles (24 KB, +1 row pad ->
//    conflict-free staging AND reads), tile loop with per-wave done-voting.
//    25.6 KB LDS + 8 waves -> 4 blocks/CU (32 waves, FULL occupancy) vs
//    R9's 2 blocks/CU at 62 KB. Tiles cover all 8192 pts -> no global tail.
//  - transpose blocks: 512-thr single 64x64 tile (R2 pattern).
// R10 falsified barrier-fused phases (82 us kernel: vmcnt(0) drain per
// __syncthreads serializes gathers); R5/R6 measured group at write floor.

union KLds {
    struct {
        float pts[3][TP + 1];    // +1 pad: stage banks (c+pt)%32 distinct,
        int   idx[QPB][NS];      //         read banks (c+base+lane)%32 2-way
        int   ndone;
    } s;                         // ~25.6 KB
    float tile[NC][65];          // 16.6 KB
};

__device__ __forceinline__ unsigned prefix_popc(unsigned long long m) {
    return __builtin_amdgcn_mbcnt_hi((unsigned)(m >> 32),
           __builtin_amdgcn_mbcnt_lo((unsigned)m, 0u));
}

__global__ __launch_bounds__(512, 8) void scan_trans_kernel(
    const float* __restrict__ xyz,    // (B, NPTS, 3)
    const float* __restrict__ nxyz,   // (B, NQ, 3)
    const float* __restrict__ feat,   // (B, NC, NPTS)
    float* __restrict__ ftr,          // (B, NPTS, NC)
    int* __restrict__ gidx,           // (B, NQ, NS)
    float* __restrict__ out,          // (B, NCH, NQ, NS)
    int ntrans)
{
    __shared__ KLds u;
    const int bx = blockIdx.x;
    const int t  = threadIdx.x;

    if (bx < ntrans) {
        // ---- feature transpose: one 64-pt x 64-ch tile, 512 thr ----
        const int b  = bx >> 7;               // 128 t-blocks per batch
        const int tl = bx & 127;
        const int n0 = tl * 64;
        const float* fb = feat + (size_t)b * NC * NPTS;
        const int pl = t & 63;
        const int c0 = t >> 6;                // 0..7
        #pragma unroll
        for (int i = 0; i < 8; ++i) {         // coalesced 256B rows
            const int c = c0 + 8 * i;
            u.tile[c][pl] = fb[(size_t)c * NPTS + n0 + pl];
        }
        __syncthreads();
        float* tb = ftr + ((size_t)b * NPTS + n0) * NC;
        #pragma unroll
        for (int i = 0; i < 8; ++i) {         // coalesced 256B per point
            const int pp = c0 + 8 * i;
            tb[(size_t)pp * NC + pl] = u.tile[pl][pp];   // (pl*65+pp)%32: free
        }
        return;
    }

    // ---- scan block: 8 queries (1 wave each), LDS-tiled over all points ----
    const int sb   = bx - ntrans;
    const int qpb  = NQ / QPB;                // 256 scan-blocks per batch
    const int b    = sb / qpb;
    const int p0   = (sb - b * qpb) * QPB;
    const int lane = t & 63;
    const int wave = t >> 6;                  // 0..7
    const int p    = p0 + wave;
    const float* xb = xyz + (size_t)b * NPTS * 3;
    int* idx_row = u.s.idx[wave];

    const float qx = nxyz[((size_t)b * NQ + p) * 3 + 0];
    const float qy = nxyz[((size_t)b * NQ + p) * 3 + 1];
    const float qz = nxyz[((size_t)b * NQ + p) * 3 + 2];

    int cnt = 0;      // wave-uniform hit count
    int first = -1;   // wave-uniform first-hit index
    if (t == 0) u.s.ndone = 0;                // visible after staging barrier

    for (int tb = 0; tb < NPTS / TP; ++tb) {
        // stage tile: 6144 dwords, 12/thread, coalesced global reads;
        // LDS writes conflict-free (pad): lanes t,t+1,t+2 -> banks pt,pt+1,pt+2
        const float* src = xb + (size_t)tb * TP * 3;
        #pragma unroll
        for (int k = 0; k < 3 * TP / 512; ++k) {
            const int g  = k * 512 + t;
            const float val = src[g];
            const int pt = g / 3;             // magic-mul
            const int c  = g - 3 * pt;
            u.s.pts[c][pt] = val;
        }
        __syncthreads();

        if (cnt < NS) {
            const int boff = tb * TP;
            // 128 pts/iter: ds_read2 pairs, dual ballot, order-correct prefix.
            // Strict per-op rounding in the reference's evaluation order:
            // q<1.0 is discontinuous -> no FMA contraction allowed.
            for (int base = 0; base < TP; base += 128) {
                const int i0 = base + lane;
                const int i1 = i0 + 64;
                const float xA = u.s.pts[0][i0], xB = u.s.pts[0][i1];
                const float yA = u.s.pts[1][i0], yB = u.s.pts[1][i1];
                const float zA = u.s.pts[2][i0], zB = u.s.pts[2][i1];

                const float dxA = __fsub_rn(qx, xA);
                const float dyA = __fsub_rn(qy, yA);
                const float dzA = __fsub_rn(qz, zA);
                const float qA  = __fadd_rn(__fadd_rn(
                                    __fmul_rn(__fmul_rn(dxA, dxA), 25.0f),
                                    __fmul_rn(__fmul_rn(dyA, dyA), 6.25f)),
                                    __fmul_rn(__fmul_rn(dzA, dzA), 25.0f));
                const float dxB = __fsub_rn(qx, xB);
                const float dyB = __fsub_rn(qy, yB);
                const float dzB = __fsub_rn(qz, zB);
                const float qB  = __fadd_rn(__fadd_rn(
                                    __fmul_rn(__fmul_rn(dxB, dxB), 25.0f),
                                    __fmul_rn(__fmul_rn(dyB, dyB), 6.25f)),
                                    __fmul_rn(__fmul_rn(dzB, dzB), 25.0f));
                const bool hitA = qA < 1.0f;
                const bool hitB = qB < 1.0f;

                const unsigned long long m0 = __ballot(hitA);
                const unsigned long long m1 = __ballot(hitB);
                if (first < 0) {              // wave-uniform
                    if (m0 != 0ull)      first = boff + base + __builtin_ctzll(m0);
                    else if (m1 != 0ull) first = boff + base + 64 + __builtin_ctzll(m1);
                }
                if (hitA) {
                    const int pos = cnt + (int)prefix_popc(m0);
                    if (pos < NS) idx_row[pos] = boff + i0;
                }
                const int c0h = __popcll(m0);
                if (hitB) {
                    const int pos = cnt + c0h + (int)prefix_popc(m1);
                    if (pos < NS) idx_row[pos] = boff + i1;
                }
                cnt += c0h + __popcll(m1);
                if (cnt >= NS) break;         // uniform early exit
            }
            if (cnt >= NS && lane == 0)
                atomicAdd(&u.s.ndone, 1);     // this wave just finished
        }
        __syncthreads();
        if (u.s.ndone == QPB) break;          // block-uniform after barrier
    }

    if (cnt < NS) {                           // <32 hits in whole cloud
        const int f = (cnt == 0) ? 0 : first; // pad (0 if empty)
        if (lane < NS && lane >= cnt) idx_row[lane] = f;
    }

    // epilogue: lanes 0..31 emit idx + channels 0..3
    if (lane < NS) {
        const int s = lane;
        const int j = idx_row[s];             // same-wave LDS RAW: safe
        gidx[((size_t)b * NQ + p) * NS + s] = j;

        const float px = xb[3 * j + 0];
        const float py = xb[3 * j + 1];
        const float pz = xb[3 * j + 2];
        const float dx = __fsub_rn(px, qx);
        const float dy = __fsub_rn(py, qy);
        const float dz = __fsub_rn(pz, qz);
        const float d2 = __fadd_rn(__fadd_rn(__fmul_rn(dx, dx), __fmul_rn(dy, dy)),
                                   __fmul_rn(dz, dz));
        const float dist = __fsqrt_rn(d2);
        const float arg  = __fdiv_rn(-__fmul_rn(dist, dist), 0.02f);
        const float density = __fmul_rn(expf(arg), 4.0f);  // /0.25 == *4 exact
        const float gd = __fdiv_rn(1.0f, density);         // inf underflow == ref

        float* ob = out + ((size_t)b * NCH * NQ + p) * NS + s;
        ob[0 * (size_t)CS] = px;
        ob[1 * (size_t)CS] = py;
        ob[2 * (size_t)CS] = pz;
        ob[3 * (size_t)CS] = gd;
    }
}

// ---------------------------------------------------------------------------
// K2: feature grouping (R4 version, measured at write-BW floor ~11-13 us).
// ---------------------------------------------------------------------------
__global__ __launch_bounds__(512, 8) void group_kernel(
    const int* __restrict__ gidx,     // (B, NQ, NS)
    const float* __restrict__ ftr,    // (B, NPTS, NC)
    float* __restrict__ out,          // (B, NCH, NQ, NS)
    int B)
{
    __shared__ float ldsc[NC][33];

    const int g = blockIdx.x;
    int b, p;
    if (B == 4) {
        b = (g & 7) >> 1;                     // XCD-pair -> batch
        p = ((g >> 3) << 1) | (g & 1);
    } else {
        b = g / NQ;
        p = g - b * NQ;
    }
    const int tid = threadIdx.x;

    const int cg = tid & 15;                  // channel group 0..15 (float4)
    const int sl = tid >> 4;                  // sample 0..31
    const int j  = gidx[((size_t)b * NQ + p) * NS + sl];
    const float4 v = ((const float4*)(ftr + ((size_t)b * NPTS + j) * NC))[cg];
    ldsc[4 * cg + 0][sl] = v.x;               // bank (4cg+i+sl)%32 -> 2-way, free
    ldsc[4 * cg + 1][sl] = v.y;
    ldsc[4 * cg + 2][sl] = v.z;
    ldsc[4 * cg + 3][sl] = v.w;
    __syncthreads();

    const int c  = tid >> 3;                  // channel 0..63
    const int s4 = (tid & 7) << 2;            // sample base 0,4,...,28
    float4 w;
    w.x = ldsc[c][s4 + 0];                    // bank (c+s4+i)%32 -> <=2-way, free
    w.y = ldsc[c][s4 + 1];
    w.z = ldsc[c][s4 + 2];
    w.w = ldsc[c][s4 + 3];
    float* op = out + (((size_t)b * NCH + 4 + c) * NQ + p) * NS + s4;
    *(float4*)op = w;                         // 8 x 128B segments per wave store
}

// ---------------------------------------------------------------------------
// Fallback (tiny ws): R1-style fused direct kernel.
// ---------------------------------------------------------------------------
__global__ __launch_bounds__(512, 8) void ellip_direct_kernel(
    const float* __restrict__ xyz,
    const float* __restrict__ nxyz,
    const float* __restrict__ feat,
    float* __restrict__ out)
{
    __shared__ int idx_s[8][NS];

    const int b    = blockIdx.y;
    const int p0   = blockIdx.x * 8;
    const int tid  = threadIdx.x;
    const int lane = tid & 63;
    const int wave = tid >> 6;
    const float* xb = xyz + (size_t)b * NPTS * 3;

    {
        const int p = p0 + wave;
        const float qx = nxyz[((size_t)b * NQ + p) * 3 + 0];
        const float qy = nxyz[((size_t)b * NQ + p) * 3 + 1];
        const float qz = nxyz[((size_t)b * NQ + p) * 3 + 2];
        int cnt = 0, first = -1;
        for (int base = 0; base < NPTS; base += 64) {
            const int i = base + lane;
            const float dx = __fsub_rn(qx, xb[i * 3 + 0]);
            const float dy = __fsub_rn(qy, xb[i * 3 + 1]);
            const float dz = __fsub_rn(qz, xb[i * 3 + 2]);
            const float t0 = __fmul_rn(__fmul_rn(dx, dx), 25.0f);
            const float t1 = __fmul_rn(__fmul_rn(dy, dy), 6.25f);
            const float t2 = __fmul_rn(__fmul_rn(dz, dz), 25.0f);
            const float qv = __fadd_rn(__fadd_rn(t0, t1), t2);
            const bool hit = qv < 1.0f;
            const unsigned long long m = __ballot(hit);
            if (first < 0 && m != 0ull) first = base + __builtin_ctzll(m);
            if (hit) {
                const int pos = cnt + __popcll(m & ((1ull << lane) - 1ull));
                if (pos < NS) idx_s[wave][pos] = i;
            }
            cnt += __popcll(m);
            if (cnt >= NS) break;
        }
        if (cnt < NS) {
            const int f = (cnt == 0) ? 0 : first;
            if (lane < NS && lane >= cnt) idx_s[wave][lane] = f;
        }
    }
    __syncthreads();

    const int s = tid & 31;
    const int h = (tid >> 5) & 1;
    const int q = tid >> 6;
    const int p = p0 + q;
    const int j = idx_s[q][s];
    float* ob = out + ((size_t)b * NCH * NQ + p) * NS + s;

    if (h == 0) {
        const float qx = nxyz[((size_t)b * NQ + p) * 3 + 0];
        const float qy = nxyz[((size_t)b * NQ + p) * 3 + 1];
        const float qz = nxyz[((size_t)b * NQ + p) * 3 + 2];
        const float px = xb[j * 3 + 0], py = xb[j * 3 + 1], pz = xb[j * 3 + 2];
        const float dx = __fsub_rn(px, qx);
        const float dy = __fsub_rn(py, qy);
        const float dz = __fsub_rn(pz, qz);
        const float d2 = __fadd_rn(__fadd_rn(__fmul_rn(dx, dx), __fmul_rn(dy, dy)),
                                   __fmul_rn(dz, dz));
        const float dist = __fsqrt_rn(d2);
        const float arg  = __fdiv_rn(-__fmul_rn(dist, dist), 0.02f);
        const float gd = __fdiv_rn(1.0f, __fmul_rn(expf(arg), 4.0f));
        ob[0 * (size_t)CS] = px;
        ob[1 * (size_t)CS] = py;
        ob[2 * (size_t)CS] = pz;
        ob[3 * (size_t)CS] = gd;
    }
    const float* fb = feat + (size_t)b * NC * NPTS + j;
    #pragma unroll 4
    for (int c = h; c < NC; c += 2)
        ob[(size_t)(4 + c) * CS] = fb[(size_t)c * NPTS];
}

extern "C" void kernel_launch(void* const* d_in, const int* in_sizes, int n_in,
                              void* d_out, int out_size, void* d_ws, size_t ws_size,
                              hipStream_t stream) {
    const float* xyz  = (const float*)d_in[0];   // (B, 8192, 3)
    const float* nxyz = (const float*)d_in[1];   // (B, 2048, 3)
    const float* feat = (const float*)d_in[2];   // (B, 64, 8192)
    float* out = (float*)d_out;                  // (B, 68, 2048, 32)

    const int B = in_sizes[0] / (NPTS * 3);
    const size_t ftr_f = (size_t)B * NPTS * NC;
    const size_t idx_f = (size_t)B * NQ * NS;
    const size_t need  = (ftr_f + idx_f) * 4;

    if (ws_size >= need) {
        float* ftr = (float*)d_ws;
        int*   idx = (int*)(ftr + ftr_f);

        const int ntrans = B * (NPTS / 64);      // 512 transpose blocks (first)
        const int nscan  = B * (NQ / QPB);       // 1024 scan blocks
        scan_trans_kernel<<<dim3(ntrans + nscan), 512, 0, stream>>>(
            xyz, nxyz, feat, ftr, idx, out, ntrans);
        group_kernel<<<dim3(B * NQ), 512, 0, stream>>>(idx, ftr, out, B);
    } else {
        ellip_direct_kernel<<<dim3(NQ / 8, B), 512, 0, stream>>>(xyz, nxyz, feat, out);
    }
}